// Round 17
// baseline (187.971 us; speedup 1.0000x reference)
//
#include <hip/hip_runtime.h>

#define SEQ   2048
#define DIM   64
#define NB    2
#define NH    16
#define NHEAD (NB * NH)
#define BK    64
#define NKT   (SEQ / BK)
#define QSCALE 0.18033688011112042f  /* log2(e)/sqrt(64) */

typedef float  f32x4  __attribute__((ext_vector_type(4)));
typedef short  bf16x8 __attribute__((ext_vector_type(8)));
typedef unsigned short u16;
typedef u16    u16x4  __attribute__((ext_vector_type(4)));
typedef u16    u16x8  __attribute__((ext_vector_type(8)));
typedef unsigned int u32x4 __attribute__((ext_vector_type(4)));

__device__ __forceinline__ short f2bf(float x) {
    unsigned u = __float_as_uint(x);
    return (short)((u + 0x7FFFu + ((u >> 16) & 1u)) >> 16);
}

__device__ __forceinline__ unsigned cvtpk(float lo, float hi) {
    unsigned r;
    asm("v_cvt_pk_bf16_f32 %0, %1, %2" : "=v"(r) : "v"(lo), "v"(hi));
    return r;
}

// async global->LDS, 16B per lane
__device__ __forceinline__ void gll16(const void* g, void* l) {
    __builtin_amdgcn_global_load_lds(
        (const __attribute__((address_space(1))) unsigned int*)g,
        (__attribute__((address_space(3))) unsigned int*)l, 16, 0, 0);
}

// ---------- pre-kernel: K f32 -> bf16, fragment-major tiles ----------
__global__ __launch_bounds__(256)
void conv_k_kernel(const float* __restrict__ K, u16* __restrict__ Kp)
{
    const int idx  = (int)blockIdx.x * 256 + (int)threadIdx.x;
    const int lane = idx & 63;
    const int s    = (idx >> 6) & 7;
    const int kt   = (idx >> 9) & 31;
    const int h    = idx >> 14;
    const int mrow = lane & 15;
    const int kg4  = (lane >> 4) << 2;
    const int row  = (s >> 1) * 16 + mrow;
    const int cb   = (s & 1) * 32 + kg4;

    const float* src = K + ((size_t)h * SEQ + (size_t)kt * 64 + row) * DIM + cb;
    const float4 a = *reinterpret_cast<const float4*>(src);
    const float4 b = *reinterpret_cast<const float4*>(src + 16);
    u16x8 o;
    o[0] = (u16)f2bf(a.x); o[1] = (u16)f2bf(a.y); o[2] = (u16)f2bf(a.z); o[3] = (u16)f2bf(a.w);
    o[4] = (u16)f2bf(b.x); o[5] = (u16)f2bf(b.y); o[6] = (u16)f2bf(b.z); o[7] = (u16)f2bf(b.w);
    *reinterpret_cast<u16x8*>(Kp + (size_t)idx * 8) = o;
}

// ---------- pre-kernel: V f32 -> bf16, V^T fragment-major tiles ----------
__global__ __launch_bounds__(256)
void conv_v_kernel(const float* __restrict__ V, u16* __restrict__ Vp)
{
    const int idx  = (int)blockIdx.x * 256 + (int)threadIdx.x;
    const int lane = idx & 63;
    const int s    = (idx >> 6) & 7;
    const int kt   = (idx >> 9) & 31;
    const int h    = idx >> 14;
    const int mrow = lane & 15;
    const int kg4  = (lane >> 4) << 2;
    const int rd   = (s >> 1) * 16 + mrow;
    const int cb   = (s & 1) * 32 + kg4;

    const float* vb = V + ((size_t)h * SEQ + (size_t)kt * 64) * DIM;
    u16x8 o;
    #pragma unroll
    for (int j = 0; j < 4; ++j) {
        o[j]     = (u16)f2bf(vb[(size_t)(cb + j) * DIM + rd]);
        o[4 + j] = (u16)f2bf(vb[(size_t)(cb + 16 + j) * DIM + rd]);
    }
    *reinterpret_cast<u16x8*>(Vp + (size_t)idx * 8) = o;
}

// ---------- pass-1 kernel: row sums -> rinv stashed in O[row][0] ----------
// 256 threads (4 waves), BQ=64, 3-buffer K pipeline, 4 blocks/CU.
__global__ __launch_bounds__(256, 4)
void sdpa_pass1_kernel(const float* __restrict__ Qp, const u16* __restrict__ Kp,
                       const int* __restrict__ Mp, float* __restrict__ Op)
{
    __shared__ u16   Ks[3][4096];
    __shared__ float Fb[SEQ];

    const int tid  = (int)threadIdx.x;
    const int lane = tid & 63;
    const int w    = tid >> 6;            // wave 0..3, owns q-rows w*16..w*16+15
    const int mrow = lane & 15;
    const int kg4  = (lane >> 4) << 2;

    // XCD-clustered: 1024 blocks, xcd = bid&7, heads [xcd*4, xcd*4+4).
    const int bid  = (int)blockIdx.x;
    const int xcd  = bid & 7;
    const int slot = bid >> 3;            // 0..127
    const int bh   = xcd * 4 + (slot >> 5);
    const int qt   = slot & 31;           // 32 q-tiles of 64 rows

    const size_t headoff = (size_t)bh * SEQ * DIM;
    const float* Qg = Qp + headoff + (size_t)qt * 64 * DIM;
    const u16*   Kh = Kp + (size_t)bh * NKT * 4096;
    const int*   Mg = Mp + (size_t)(bh / NH) * SEQ;
    float*       Rv = Op + headoff + (size_t)qt * 64 * DIM;  // rinv at O[row][0]

    // mask -> additive log2-domain bias in LDS (once)
    {
        const int4 m0 = *reinterpret_cast<const int4*>(Mg + tid * 8);
        const int4 m1 = *reinterpret_cast<const int4*>(Mg + tid * 8 + 4);
        float4 f0, f1;
        f0.x = m0.x ? -1.0e9f : 0.0f; f0.y = m0.y ? -1.0e9f : 0.0f;
        f0.z = m0.z ? -1.0e9f : 0.0f; f0.w = m0.w ? -1.0e9f : 0.0f;
        f1.x = m1.x ? -1.0e9f : 0.0f; f1.y = m1.y ? -1.0e9f : 0.0f;
        f1.z = m1.z ? -1.0e9f : 0.0f; f1.w = m1.w ? -1.0e9f : 0.0f;
        *reinterpret_cast<float4*>(&Fb[tid * 8])     = f0;
        *reinterpret_cast<float4*>(&Fb[tid * 8 + 4]) = f1;
    }

    // Q fragments (scale folded)
    bf16x8 qf0, qf1;
    {
        const float* qrow = Qg + (size_t)(w * 16 + mrow) * DIM;
        const float4 a = *reinterpret_cast<const float4*>(qrow + kg4);
        const float4 b = *reinterpret_cast<const float4*>(qrow + 16 + kg4);
        const float4 c = *reinterpret_cast<const float4*>(qrow + 32 + kg4);
        const float4 d = *reinterpret_cast<const float4*>(qrow + 48 + kg4);
        qf0[0] = f2bf(a.x * QSCALE); qf0[1] = f2bf(a.y * QSCALE);
        qf0[2] = f2bf(a.z * QSCALE); qf0[3] = f2bf(a.w * QSCALE);
        qf0[4] = f2bf(b.x * QSCALE); qf0[5] = f2bf(b.y * QSCALE);
        qf0[6] = f2bf(b.z * QSCALE); qf0[7] = f2bf(b.w * QSCALE);
        qf1[0] = f2bf(c.x * QSCALE); qf1[1] = f2bf(c.y * QSCALE);
        qf1[2] = f2bf(c.z * QSCALE); qf1[3] = f2bf(c.w * QSCALE);
        qf1[4] = f2bf(d.x * QSCALE); qf1[5] = f2bf(d.y * QSCALE);
        qf1[6] = f2bf(d.z * QSCALE); qf1[7] = f2bf(d.w * QSCALE);
    }
    __syncthreads();   // Fb visible

    const int so  = tid * 8;     // 256 thr * 16B = half a tile
    const int lo8 = lane * 8;

    // prologue: tiles 0,1 (2 GLLs each)
    gll16(Kh + so, &Ks[0][so]);
    gll16(Kh + so + 2048, &Ks[0][so + 2048]);
    gll16(Kh + 4096 + so, &Ks[1][so]);
    gll16(Kh + 4096 + so + 2048, &Ks[1][so + 2048]);

    float lsum = 0.f;
    int bcur = 0, bpre = 2;

    for (int kt = 0; kt < NKT; ++kt) {
        // queue at top: [G(kt)x2, G(kt+1)x2] -> vmcnt(2) retires G(kt) pair
        asm volatile("s_waitcnt vmcnt(2)" ::: "memory");
        __builtin_amdgcn_s_barrier();
        {   // prefetch tile kt+2 into buffer read at iter kt-1 (barrier-safe)
            const size_t nt = (size_t)((kt + 2) & (NKT - 1)) * 4096;
            gll16(Kh + nt + so, &Ks[bpre][so]);
            gll16(Kh + nt + so + 2048, &Ks[bpre][so + 2048]);
        }
        __builtin_amdgcn_sched_barrier(0);

        const u16* kp = &Ks[bcur][lo8];
        const int k0 = kt * BK;
        #pragma unroll
        for (int t = 0; t < 4; ++t) {
            const bf16x8 kf0 = *reinterpret_cast<const bf16x8*>(kp + (2 * t) * 512);
            const bf16x8 kf1 = *reinterpret_cast<const bf16x8*>(kp + (2 * t + 1) * 512);
            f32x4 a = {0.f, 0.f, 0.f, 0.f};
            a = __builtin_amdgcn_mfma_f32_16x16x32_bf16(kf0, qf0, a, 0, 0, 0);
            a = __builtin_amdgcn_mfma_f32_16x16x32_bf16(kf1, qf1, a, 0, 0, 0);
            const float4 b = *reinterpret_cast<const float4*>(&Fb[k0 + t * 16 + kg4]);
            lsum += __builtin_amdgcn_exp2f(a[0] + b.x);
            lsum += __builtin_amdgcn_exp2f(a[1] + b.y);
            lsum += __builtin_amdgcn_exp2f(a[2] + b.z);
            lsum += __builtin_amdgcn_exp2f(a[3] + b.w);
        }

        bcur = (bcur == 2) ? 0 : bcur + 1;
        bpre = (bpre == 2) ? 0 : bpre + 1;
    }

    lsum += __shfl_xor(lsum, 16);
    lsum += __shfl_xor(lsum, 32);
    if (lane < 16)
        Rv[(size_t)(w * 16 + lane) * DIM] = 1.0f / lsum;
}

// ---------- pass-2 kernel: 1024 threads, BQ=256, 3-buffer, 1 barrier/iter ----------
__global__ __launch_bounds__(1024, 1)
void sdpa_pass2_kernel(const float* __restrict__ Qp, const u16* __restrict__ Kp,
                       const u16* __restrict__ Vp, const int* __restrict__ Mp,
                       float* __restrict__ Op, float* __restrict__ Pg_)
{
    __shared__ u16   Ks[3][4096];
    __shared__ u16   Vs[3][4096];
    __shared__ float Fb[SEQ];
    __shared__ u16   Pst[16][16][68];

    const int tid  = (int)threadIdx.x;
    const int lane = tid & 63;
    const int w    = tid >> 6;            // wave 0..15, owns q-rows w*16..w*16+15
    const int mrow = lane & 15;
    const int kg4  = (lane >> 4) << 2;

    const int bid  = (int)blockIdx.x;
    const int xcd  = bid & 7;
    const int slot = bid >> 3;            // 0..31
    const int bh   = xcd * 4 + (slot >> 3);
    const int qt   = slot & 7;            // 8 q-tiles of 256 rows

    const size_t headoff = (size_t)bh * SEQ * DIM;
    const float* Qg = Qp + headoff + (size_t)qt * 256 * DIM;
    const u16*   Kh = Kp + (size_t)bh * NKT * 4096;
    const u16*   Vh = Vp + (size_t)bh * NKT * 4096;
    const int*   Mg = Mp + (size_t)(bh / NH) * SEQ;
    float*       Og = Op + headoff + (size_t)qt * 256 * DIM;
    float*       Pg = Pg_ + ((size_t)bh * SEQ + (size_t)qt * 256) * SEQ;

    // rinv stashed by pass 1 at O[row][0] (this block owns these rows)
    const float rinv = Og[(size_t)(w * 16 + mrow) * DIM];

    // mask -> additive log2-domain bias in LDS (once)
    {
        const int2 m0 = *reinterpret_cast<const int2*>(Mg + tid * 2);
        float2 f0;
        f0.x = m0.x ? -1.0e9f : 0.0f;
        f0.y = m0.y ? -1.0e9f : 0.0f;
        *reinterpret_cast<float2*>(&Fb[tid * 2]) = f0;
    }

    // Q fragments (scale folded)
    bf16x8 qf0, qf1;
    {
        const float* qrow = Qg + (size_t)(w * 16 + mrow) * DIM;
        const float4 a = *reinterpret_cast<const float4*>(qrow + kg4);
        const float4 b = *reinterpret_cast<const float4*>(qrow + 16 + kg4);
        const float4 c = *reinterpret_cast<const float4*>(qrow + 32 + kg4);
        const float4 d = *reinterpret_cast<const float4*>(qrow + 48 + kg4);
        qf0[0] = f2bf(a.x * QSCALE); qf0[1] = f2bf(a.y * QSCALE);
        qf0[2] = f2bf(a.z * QSCALE); qf0[3] = f2bf(a.w * QSCALE);
        qf0[4] = f2bf(b.x * QSCALE); qf0[5] = f2bf(b.y * QSCALE);
        qf0[6] = f2bf(b.z * QSCALE); qf0[7] = f2bf(b.w * QSCALE);
        qf1[0] = f2bf(c.x * QSCALE); qf1[1] = f2bf(c.y * QSCALE);
        qf1[2] = f2bf(c.z * QSCALE); qf1[3] = f2bf(c.w * QSCALE);
        qf1[4] = f2bf(d.x * QSCALE); qf1[5] = f2bf(d.y * QSCALE);
        qf1[6] = f2bf(d.z * QSCALE); qf1[7] = f2bf(d.w * QSCALE);
    }
    __syncthreads();   // Fb visible

    // staging roles: waves 0-7 stage K, waves 8-15 stage V
    const int so8 = (tid & 511) * 8;
    const int lo8 = lane * 8;

    f32x4 oacc[4];
    #pragma unroll
    for (int n = 0; n < 4; ++n) {
        oacc[n][0] = 0.f; oacc[n][1] = 0.f; oacc[n][2] = 0.f; oacc[n][3] = 0.f;
    }

    if (w < 8) {
        gll16(Kh + so8, &Ks[0][so8]);
        gll16(Kh + 4096 + so8, &Ks[1][so8]);
    } else {
        gll16(Vh + so8, &Vs[0][so8]);
        gll16(Vh + 4096 + so8, &Vs[1][so8]);
    }
    asm volatile("s_waitcnt vmcnt(1)" ::: "memory");   // peel: tile-0 GLL retired
    __builtin_amdgcn_s_barrier();
    int bcur = 0, bpre = 2;

    float* PgW = Pg + (size_t)(w * 16) * SEQ;

    for (int kt = 0; kt < NKT; ++kt) {
        // steady (kt>=2): [G(kt), S(kt-2)x4, G(kt+1), S(kt-1)x4] = 10 -> vmcnt(9)
        // kt==1: [G(1), G(2), S(0)x4] = 6 -> vmcnt(5).  kt==0 covered by peel.
        if (kt == 1) { asm volatile("s_waitcnt vmcnt(5)" ::: "memory"); }
        else         { asm volatile("s_waitcnt vmcnt(9)" ::: "memory"); }
        __builtin_amdgcn_s_barrier();
        {
            const size_t nt = (size_t)((kt + 2) & (NKT - 1)) * 4096;
            if (w < 8) gll16(Kh + nt + so8, &Ks[bpre][so8]);
            else       gll16(Vh + nt + so8, &Vs[bpre][so8]);
        }
        __builtin_amdgcn_sched_barrier(0);

        const u16* kp = &Ks[bcur][lo8];
        const u16* vp = &Vs[bcur][lo8];
        const int k0 = kt * BK;
        bf16x8 pf0, pf1;

        #pragma unroll
        for (int half = 0; half < 2; ++half) {
            f32x4 p[2];
            #pragma unroll
            for (int i = 0; i < 2; ++i) {
                const int t = half * 2 + i;
                const bf16x8 kf0 = *reinterpret_cast<const bf16x8*>(kp + (2 * t) * 512);
                const bf16x8 kf1 = *reinterpret_cast<const bf16x8*>(kp + (2 * t + 1) * 512);
                f32x4 a = {0.f, 0.f, 0.f, 0.f};
                a = __builtin_amdgcn_mfma_f32_16x16x32_bf16(kf0, qf0, a, 0, 0, 0);
                a = __builtin_amdgcn_mfma_f32_16x16x32_bf16(kf1, qf1, a, 0, 0, 0);
                const float4 b = *reinterpret_cast<const float4*>(&Fb[k0 + t * 16 + kg4]);
                p[i][0] = __builtin_amdgcn_exp2f(a[0] + b.x) * rinv;
                p[i][1] = __builtin_amdgcn_exp2f(a[1] + b.y) * rinv;
                p[i][2] = __builtin_amdgcn_exp2f(a[2] + b.z) * rinv;
                p[i][3] = __builtin_amdgcn_exp2f(a[3] + b.w) * rinv;
            }
            const u32x4 packed = { cvtpk(p[0][0], p[0][1]), cvtpk(p[0][2], p[0][3]),
                                   cvtpk(p[1][0], p[1][1]), cvtpk(p[1][2], p[1][3]) };
            if (half == 0) pf0 = __builtin_bit_cast(bf16x8, packed);
            else           pf1 = __builtin_bit_cast(bf16x8, packed);
        }

        // stage P tile (bf16) into wave-private LDS
        {
            const u16x4* f0 = reinterpret_cast<const u16x4*>(&pf0);
            const u16x4* f1 = reinterpret_cast<const u16x4*>(&pf1);
            *reinterpret_cast<u16x4*>(&Pst[w][mrow][kg4])      = f0[0];
            *reinterpret_cast<u16x4*>(&Pst[w][mrow][16 + kg4]) = f0[1];
            *reinterpret_cast<u16x4*>(&Pst[w][mrow][32 + kg4]) = f1[0];
            *reinterpret_cast<u16x4*>(&Pst[w][mrow][48 + kg4]) = f1[1];
        }

        #pragma unroll
        for (int n = 0; n < 4; ++n) {
            const bf16x8 vf0 = *reinterpret_cast<const bf16x8*>(vp + (2 * n) * 512);
            const bf16x8 vf1 = *reinterpret_cast<const bf16x8*>(vp + (2 * n + 1) * 512);
            oacc[n] = __builtin_amdgcn_mfma_f32_16x16x32_bf16(pf0, vf0, oacc[n], 0, 0, 0);
            oacc[n] = __builtin_amdgcn_mfma_f32_16x16x32_bf16(pf1, vf1, oacc[n], 0, 0, 0);
        }

        // coalesced P store: instr j covers 4 rows x 256B contiguous
        #pragma unroll
        for (int j = 0; j < 4; ++j) {
            const u16x4 r = *reinterpret_cast<const u16x4*>(
                &Pst[w][j * 4 + (lane >> 4)][(lane & 15) * 4]);
            float4 f;
            f.x = __uint_as_float((unsigned)r[0] << 16);
            f.y = __uint_as_float((unsigned)r[1] << 16);
            f.z = __uint_as_float((unsigned)r[2] << 16);
            f.w = __uint_as_float((unsigned)r[3] << 16);
            *reinterpret_cast<float4*>(
                PgW + (size_t)(j * 4 + (lane >> 4)) * SEQ + k0 + 4 * (lane & 15)) = f;
        }

        bcur = (bcur == 2) ? 0 : bcur + 1;
        bpre = (bpre == 2) ? 0 : bpre + 1;
    }

    #pragma unroll
    for (int n = 0; n < 4; ++n) {
        #pragma unroll
        for (int r = 0; r < 4; ++r)
            Og[(size_t)(w * 16 + kg4 + r) * DIM + n * 16 + mrow] = oacc[n][r];
    }
}

extern "C" void kernel_launch(void* const* d_in, const int* in_sizes, int n_in,
                              void* d_out, int out_size, void* d_ws, size_t ws_size,
                              hipStream_t stream) {
    const float* Q = (const float*)d_in[0];
    const float* K = (const float*)d_in[1];
    const float* V = (const float*)d_in[2];
    const int*   M = (const int*)d_in[3];
    float* O = (float*)d_out;
    float* P = O + (size_t)NB * NH * SEQ * DIM;

    u16* Kp = (u16*)d_ws;                                   // 8 MB
    u16* Vp = Kp + (size_t)NHEAD * SEQ * DIM;               // 8 MB (exactly 16 MB total)

    const int conv_blocks = NHEAD * NKT * 8 * 64 / 256;     // 2048
    conv_k_kernel<<<dim3(conv_blocks), dim3(256), 0, stream>>>(K, Kp);
    conv_v_kernel<<<dim3(conv_blocks), dim3(256), 0, stream>>>(V, Vp);

    sdpa_pass1_kernel<<<dim3(NHEAD * 32), dim3(256, 1, 1), 0, stream>>>(Q, Kp, M, O);
    sdpa_pass2_kernel<<<dim3(NHEAD * 8), dim3(1024, 1, 1), 0, stream>>>(Q, Kp, Vp, M, O, P);
}

// Round 18
// 179.937 us; speedup vs baseline: 1.0446x; 1.0446x over previous
//
#include <hip/hip_runtime.h>

#define SEQ   2048
#define DIM   64
#define NB    2
#define NH    16
#define NHEAD (NB * NH)
#define BQ    256
#define BK    64
#define NKT   (SEQ / BK)
#define NQT   (SEQ / BQ)
#define QSCALE 0.18033688011112042f  /* log2(e)/sqrt(64) */

typedef float  f32x4  __attribute__((ext_vector_type(4)));
typedef short  bf16x8 __attribute__((ext_vector_type(8)));
typedef unsigned short u16;
typedef u16    u16x4  __attribute__((ext_vector_type(4)));
typedef u16    u16x8  __attribute__((ext_vector_type(8)));
typedef unsigned int u32x4 __attribute__((ext_vector_type(4)));

__device__ __forceinline__ short f2bf(float x) {
    unsigned u = __float_as_uint(x);
    return (short)((u + 0x7FFFu + ((u >> 16) & 1u)) >> 16);
}

__device__ __forceinline__ unsigned cvtpk(float lo, float hi) {
    unsigned r;
    asm("v_cvt_pk_bf16_f32 %0, %1, %2" : "=v"(r) : "v"(lo), "v"(hi));
    return r;
}

// async global->LDS, 16B per lane
__device__ __forceinline__ void gll16(const void* g, void* l) {
    __builtin_amdgcn_global_load_lds(
        (const __attribute__((address_space(1))) unsigned int*)g,
        (__attribute__((address_space(3))) unsigned int*)l, 16, 0, 0);
}

// ---------- pre-kernel: K f32 -> bf16, fragment-major tiles ----------
__global__ __launch_bounds__(256)
void conv_k_kernel(const float* __restrict__ K, u16* __restrict__ Kp)
{
    const int idx  = (int)blockIdx.x * 256 + (int)threadIdx.x;
    const int lane = idx & 63;
    const int s    = (idx >> 6) & 7;
    const int kt   = (idx >> 9) & 31;
    const int h    = idx >> 14;
    const int mrow = lane & 15;
    const int kg4  = (lane >> 4) << 2;
    const int row  = (s >> 1) * 16 + mrow;
    const int cb   = (s & 1) * 32 + kg4;

    const float* src = K + ((size_t)h * SEQ + (size_t)kt * 64 + row) * DIM + cb;
    const float4 a = *reinterpret_cast<const float4*>(src);
    const float4 b = *reinterpret_cast<const float4*>(src + 16);
    u16x8 o;
    o[0] = (u16)f2bf(a.x); o[1] = (u16)f2bf(a.y); o[2] = (u16)f2bf(a.z); o[3] = (u16)f2bf(a.w);
    o[4] = (u16)f2bf(b.x); o[5] = (u16)f2bf(b.y); o[6] = (u16)f2bf(b.z); o[7] = (u16)f2bf(b.w);
    *reinterpret_cast<u16x8*>(Kp + (size_t)idx * 8) = o;
}

// ---------- pre-kernel: V f32 -> bf16, V^T fragment-major tiles ----------
__global__ __launch_bounds__(256)
void conv_v_kernel(const float* __restrict__ V, u16* __restrict__ Vp)
{
    const int idx  = (int)blockIdx.x * 256 + (int)threadIdx.x;
    const int lane = idx & 63;
    const int s    = (idx >> 6) & 7;
    const int kt   = (idx >> 9) & 31;
    const int h    = idx >> 14;
    const int mrow = lane & 15;
    const int kg4  = (lane >> 4) << 2;
    const int rd   = (s >> 1) * 16 + mrow;
    const int cb   = (s & 1) * 32 + kg4;

    const float* vb = V + ((size_t)h * SEQ + (size_t)kt * 64) * DIM;
    u16x8 o;
    #pragma unroll
    for (int j = 0; j < 4; ++j) {
        o[j]     = (u16)f2bf(vb[(size_t)(cb + j) * DIM + rd]);
        o[4 + j] = (u16)f2bf(vb[(size_t)(cb + 16 + j) * DIM + rd]);
    }
    *reinterpret_cast<u16x8*>(Vp + (size_t)idx * 8) = o;
}

// ---------- main fused kernel: 1024 threads, BQ=256, 3-buffer, 1 barrier/iter ----------
// Pass 1 processes TWO K-tiles per barrier-join (even tile -> Ks slot, odd -> Vs slot).
__global__ __launch_bounds__(1024, 1)
void sdpa_main_kernel(const float* __restrict__ Qp, const u16* __restrict__ Kp,
                      const u16* __restrict__ Vp, const int* __restrict__ Mp,
                      float* __restrict__ Op, float* __restrict__ Pg_)
{
    __shared__ u16   Ks[3][4096];
    __shared__ u16   Vs[3][4096];
    __shared__ float Fb[SEQ];
    __shared__ u16   Pst[16][16][68];  // per-wave P tile (bf16), padded rows

    const int tid  = (int)threadIdx.x;
    const int lane = tid & 63;
    const int w    = tid >> 6;            // wave 0..15, owns q-rows w*16..w*16+15
    const int mrow = lane & 15;
    const int kg4  = (lane >> 4) << 2;

    // XCD-clustered decomposition: 256 blocks (1/CU), xcd = bid & 7.
    const int bid  = (int)blockIdx.x;
    const int xcd  = bid & 7;
    const int slot = bid >> 3;            // 0..31
    const int bh   = xcd * 4 + (slot >> 3);
    const int qt   = slot & 7;            // 8 q-tiles of 256 rows

    const size_t headoff = (size_t)bh * SEQ * DIM;
    const float* Qg = Qp + headoff + (size_t)qt * BQ * DIM;
    const u16*   Kh = Kp + (size_t)bh * NKT * 4096;
    const u16*   Vh = Vp + (size_t)bh * NKT * 4096;
    const int*   Mg = Mp + (size_t)(bh / NH) * SEQ;
    float*       Og = Op + headoff + (size_t)qt * BQ * DIM;
    float*       Pg = Pg_ + ((size_t)bh * SEQ + (size_t)qt * BQ) * SEQ;

    // ---- mask -> additive log2-domain bias in LDS (once) ----
    {
        const int2 m0 = *reinterpret_cast<const int2*>(Mg + tid * 2);
        float2 f0;
        f0.x = m0.x ? -1.0e9f : 0.0f;
        f0.y = m0.y ? -1.0e9f : 0.0f;
        *reinterpret_cast<float2*>(&Fb[tid * 2]) = f0;
    }

    // ---- Q fragments: global -> regs directly (scale folded) ----
    bf16x8 qf0, qf1;
    {
        const float* qrow = Qg + (size_t)(w * 16 + mrow) * DIM;
        const float4 a = *reinterpret_cast<const float4*>(qrow + kg4);
        const float4 b = *reinterpret_cast<const float4*>(qrow + 16 + kg4);
        const float4 c = *reinterpret_cast<const float4*>(qrow + 32 + kg4);
        const float4 d = *reinterpret_cast<const float4*>(qrow + 48 + kg4);
        qf0[0] = f2bf(a.x * QSCALE); qf0[1] = f2bf(a.y * QSCALE);
        qf0[2] = f2bf(a.z * QSCALE); qf0[3] = f2bf(a.w * QSCALE);
        qf0[4] = f2bf(b.x * QSCALE); qf0[5] = f2bf(b.y * QSCALE);
        qf0[6] = f2bf(b.z * QSCALE); qf0[7] = f2bf(b.w * QSCALE);
        qf1[0] = f2bf(c.x * QSCALE); qf1[1] = f2bf(c.y * QSCALE);
        qf1[2] = f2bf(c.z * QSCALE); qf1[3] = f2bf(c.w * QSCALE);
        qf1[4] = f2bf(d.x * QSCALE); qf1[5] = f2bf(d.y * QSCALE);
        qf1[6] = f2bf(d.z * QSCALE); qf1[7] = f2bf(d.w * QSCALE);
    }
    __syncthreads();   // Fb visible to all waves

    // staging roles: waves 0-7 handle even tiles / K, waves 8-15 odd tiles / V
    const int so8 = (tid & 511) * 8;      // offset within an 8KB tile (u16 units)
    const int lo8 = lane * 8;             // lane fragment offset in a frag slot

    // ===== pass 1: lsum — TWO tiles per join (16 iters) =====
    if (w < 8) {
        gll16(Kh + so8, &Ks[0][so8]);                      // tile 0
        gll16(Kh + (size_t)2 * 4096 + so8, &Ks[1][so8]);   // tile 2
    } else {
        gll16(Kh + (size_t)1 * 4096 + so8, &Vs[0][so8]);   // tile 1
        gll16(Kh + (size_t)3 * 4096 + so8, &Vs[1][so8]);   // tile 3
    }

    float lsum = 0.f;
    int bcur = 0, bpre = 2;

    for (int j = 0; j < NKT / 2; ++j) {
        // per-wave queue at top: [G(j), G(j+1)] -> vmcnt(1) retires G(j)
        asm volatile("s_waitcnt vmcnt(1)" ::: "memory");
        __builtin_amdgcn_s_barrier();
        {   // prefetch tile-pair j+2 into slot read at iter j-1 (barrier-safe)
            const int jn = (j + 2) & (NKT / 2 - 1);
            if (w < 8) gll16(Kh + (size_t)(2 * jn) * 4096 + so8, &Ks[bpre][so8]);
            else       gll16(Kh + (size_t)(2 * jn + 1) * 4096 + so8, &Vs[bpre][so8]);
        }
        __builtin_amdgcn_sched_barrier(0);

        const u16* kpe = &Ks[bcur][lo8];   // even tile (2j)
        const u16* kpo = &Vs[bcur][lo8];   // odd tile (2j+1)
        const int k0e = (2 * j) * BK;
        #pragma unroll
        for (int t = 0; t < 4; ++t) {
            const bf16x8 kf0 = *reinterpret_cast<const bf16x8*>(kpe + (2 * t) * 512);
            const bf16x8 kf1 = *reinterpret_cast<const bf16x8*>(kpe + (2 * t + 1) * 512);
            f32x4 a = {0.f, 0.f, 0.f, 0.f};
            a = __builtin_amdgcn_mfma_f32_16x16x32_bf16(kf0, qf0, a, 0, 0, 0);
            a = __builtin_amdgcn_mfma_f32_16x16x32_bf16(kf1, qf1, a, 0, 0, 0);
            const float4 b = *reinterpret_cast<const float4*>(&Fb[k0e + t * 16 + kg4]);
            lsum += __builtin_amdgcn_exp2f(a[0] + b.x);
            lsum += __builtin_amdgcn_exp2f(a[1] + b.y);
            lsum += __builtin_amdgcn_exp2f(a[2] + b.z);
            lsum += __builtin_amdgcn_exp2f(a[3] + b.w);
        }
        #pragma unroll
        for (int t = 0; t < 4; ++t) {
            const bf16x8 kf0 = *reinterpret_cast<const bf16x8*>(kpo + (2 * t) * 512);
            const bf16x8 kf1 = *reinterpret_cast<const bf16x8*>(kpo + (2 * t + 1) * 512);
            f32x4 a = {0.f, 0.f, 0.f, 0.f};
            a = __builtin_amdgcn_mfma_f32_16x16x32_bf16(kf0, qf0, a, 0, 0, 0);
            a = __builtin_amdgcn_mfma_f32_16x16x32_bf16(kf1, qf1, a, 0, 0, 0);
            const float4 b = *reinterpret_cast<const float4*>(&Fb[k0e + BK + t * 16 + kg4]);
            lsum += __builtin_amdgcn_exp2f(a[0] + b.x);
            lsum += __builtin_amdgcn_exp2f(a[1] + b.y);
            lsum += __builtin_amdgcn_exp2f(a[2] + b.z);
            lsum += __builtin_amdgcn_exp2f(a[3] + b.w);
        }

        bcur = (bcur == 2) ? 0 : bcur + 1;
        bpre = (bpre == 2) ? 0 : bpre + 1;
    }

    // drain leftover wraparound prefetches before pass 2 re-stages same buffers
    asm volatile("s_waitcnt vmcnt(0)" ::: "memory");

    lsum += __shfl_xor(lsum, 16);
    lsum += __shfl_xor(lsum, 32);
    const float rinv = 1.0f / lsum;

    __builtin_amdgcn_s_barrier();   // all waves drained before pass-2 staging

    // ===== pass 2: P -> LDS transpose -> coalesced global + PV accumulate =====
    f32x4 oacc[4];
    #pragma unroll
    for (int n = 0; n < 4; ++n) {
        oacc[n][0] = 0.f; oacc[n][1] = 0.f; oacc[n][2] = 0.f; oacc[n][3] = 0.f;
    }

    if (w < 8) {
        gll16(Kh + so8, &Ks[0][so8]);
        gll16(Kh + 4096 + so8, &Ks[1][so8]);
    } else {
        gll16(Vh + so8, &Vs[0][so8]);
        gll16(Vh + 4096 + so8, &Vs[1][so8]);
    }
    asm volatile("s_waitcnt vmcnt(1)" ::: "memory");   // peel: tile-0 GLL retired
    __builtin_amdgcn_s_barrier();
    bcur = 0; bpre = 2;

    float* PgW = Pg + (size_t)(w * 16) * SEQ;   // this wave's 16 P rows

    for (int kt = 0; kt < NKT; ++kt) {
        // per-wave queue at top (steady, kt>=2):
        //   [G(kt), S(kt-2)x4, G(kt+1), S(kt-1)x4] = 10 -> vmcnt(9) retires G(kt)
        // kt==1: [G(1), G(2), S(0)x4] = 6 -> vmcnt(5).  kt==0 covered by peel.
        if (kt == 1) { asm volatile("s_waitcnt vmcnt(5)" ::: "memory"); }
        else         { asm volatile("s_waitcnt vmcnt(9)" ::: "memory"); }
        __builtin_amdgcn_s_barrier();
        {   // prefetch tile kt+2 into buffer read at iter kt-1 (safe per barrier)
            const size_t nt = (size_t)((kt + 2) & (NKT - 1)) * 4096;
            if (w < 8) gll16(Kh + nt + so8, &Ks[bpre][so8]);
            else       gll16(Vh + nt + so8, &Vs[bpre][so8]);
        }
        __builtin_amdgcn_sched_barrier(0);

        const u16* kp = &Ks[bcur][lo8];
        const u16* vp = &Vs[bcur][lo8];
        const int k0 = kt * BK;
        bf16x8 pf0, pf1;

        #pragma unroll
        for (int half = 0; half < 2; ++half) {
            f32x4 p[2];
            #pragma unroll
            for (int i = 0; i < 2; ++i) {
                const int t = half * 2 + i;
                const bf16x8 kf0 = *reinterpret_cast<const bf16x8*>(kp + (2 * t) * 512);
                const bf16x8 kf1 = *reinterpret_cast<const bf16x8*>(kp + (2 * t + 1) * 512);
                f32x4 a = {0.f, 0.f, 0.f, 0.f};
                a = __builtin_amdgcn_mfma_f32_16x16x32_bf16(kf0, qf0, a, 0, 0, 0);
                a = __builtin_amdgcn_mfma_f32_16x16x32_bf16(kf1, qf1, a, 0, 0, 0);
                const float4 b = *reinterpret_cast<const float4*>(&Fb[k0 + t * 16 + kg4]);
                p[i][0] = __builtin_amdgcn_exp2f(a[0] + b.x) * rinv;
                p[i][1] = __builtin_amdgcn_exp2f(a[1] + b.y) * rinv;
                p[i][2] = __builtin_amdgcn_exp2f(a[2] + b.z) * rinv;
                p[i][3] = __builtin_amdgcn_exp2f(a[3] + b.w) * rinv;
            }
            const u32x4 packed = { cvtpk(p[0][0], p[0][1]), cvtpk(p[0][2], p[0][3]),
                                   cvtpk(p[1][0], p[1][1]), cvtpk(p[1][2], p[1][3]) };
            if (half == 0) pf0 = __builtin_bit_cast(bf16x8, packed);
            else           pf1 = __builtin_bit_cast(bf16x8, packed);
        }

        // stage P tile (bf16) into wave-private LDS
        {
            const u16x4* f0 = reinterpret_cast<const u16x4*>(&pf0);
            const u16x4* f1 = reinterpret_cast<const u16x4*>(&pf1);
            *reinterpret_cast<u16x4*>(&Pst[w][mrow][kg4])      = f0[0];
            *reinterpret_cast<u16x4*>(&Pst[w][mrow][16 + kg4]) = f0[1];
            *reinterpret_cast<u16x4*>(&Pst[w][mrow][32 + kg4]) = f1[0];
            *reinterpret_cast<u16x4*>(&Pst[w][mrow][48 + kg4]) = f1[1];
        }

        #pragma unroll
        for (int n = 0; n < 4; ++n) {
            const bf16x8 vf0 = *reinterpret_cast<const bf16x8*>(vp + (2 * n) * 512);
            const bf16x8 vf1 = *reinterpret_cast<const bf16x8*>(vp + (2 * n + 1) * 512);
            oacc[n] = __builtin_amdgcn_mfma_f32_16x16x32_bf16(pf0, vf0, oacc[n], 0, 0, 0);
            oacc[n] = __builtin_amdgcn_mfma_f32_16x16x32_bf16(pf1, vf1, oacc[n], 0, 0, 0);
        }

        // coalesced P store: instr j covers rows w*16+j*4..+3, 256B/row contiguous
        #pragma unroll
        for (int j = 0; j < 4; ++j) {
            const u16x4 r = *reinterpret_cast<const u16x4*>(
                &Pst[w][j * 4 + (lane >> 4)][(lane & 15) * 4]);
            float4 f;
            f.x = __uint_as_float((unsigned)r[0] << 16);
            f.y = __uint_as_float((unsigned)r[1] << 16);
            f.z = __uint_as_float((unsigned)r[2] << 16);
            f.w = __uint_as_float((unsigned)r[3] << 16);
            *reinterpret_cast<float4*>(
                PgW + (size_t)(j * 4 + (lane >> 4)) * SEQ + k0 + 4 * (lane & 15)) = f;
        }

        bcur = (bcur == 2) ? 0 : bcur + 1;
        bpre = (bpre == 2) ? 0 : bpre + 1;
    }

    #pragma unroll
    for (int n = 0; n < 4; ++n) {
        #pragma unroll
        for (int r = 0; r < 4; ++r)
            Og[(size_t)(w * 16 + kg4 + r) * DIM + n * 16 + mrow] = oacc[n][r];
    }
}

extern "C" void kernel_launch(void* const* d_in, const int* in_sizes, int n_in,
                              void* d_out, int out_size, void* d_ws, size_t ws_size,
                              hipStream_t stream) {
    const float* Q = (const float*)d_in[0];
    const float* K = (const float*)d_in[1];
    const float* V = (const float*)d_in[2];
    const int*   M = (const int*)d_in[3];
    float* O = (float*)d_out;
    float* P = O + (size_t)NB * NH * SEQ * DIM;

    u16* Kp = (u16*)d_ws;                                   // 8 MB
    u16* Vp = Kp + (size_t)NHEAD * SEQ * DIM;               // 8 MB (total exactly 16 MB)

    const int conv_blocks = NHEAD * NKT * 8 * 64 / 256;     // 2048
    conv_k_kernel<<<dim3(conv_blocks), dim3(256), 0, stream>>>(K, Kp);
    conv_v_kernel<<<dim3(conv_blocks), dim3(256), 0, stream>>>(V, Vp);

    sdpa_main_kernel<<<dim3(NHEAD * NQT), dim3(1024, 1, 1), 0, stream>>>(Q, Kp, Vp, M, O, P);
}

// Round 19
// 162.949 us; speedup vs baseline: 1.1536x; 1.1043x over previous
//
#include <hip/hip_runtime.h>

#define SEQ   2048
#define DIM   64
#define NB    2
#define NH    16
#define NHEAD (NB * NH)
#define BQ    256
#define BK    64
#define NKT   (SEQ / BK)
#define NQT   (SEQ / BQ)
#define QSCALE 0.18033688011112042f  /* log2(e)/sqrt(64) */

typedef float  f32x4  __attribute__((ext_vector_type(4)));
typedef short  bf16x8 __attribute__((ext_vector_type(8)));
typedef unsigned short u16;
typedef u16    u16x4  __attribute__((ext_vector_type(4)));
typedef u16    u16x8  __attribute__((ext_vector_type(8)));
typedef unsigned int u32x4 __attribute__((ext_vector_type(4)));

__device__ __forceinline__ short f2bf(float x) {
    unsigned u = __float_as_uint(x);
    return (short)((u + 0x7FFFu + ((u >> 16) & 1u)) >> 16);
}

__device__ __forceinline__ unsigned cvtpk(float lo, float hi) {
    unsigned r;
    asm("v_cvt_pk_bf16_f32 %0, %1, %2" : "=v"(r) : "v"(lo), "v"(hi));
    return r;
}

// async global->LDS, 16B per lane
__device__ __forceinline__ void gll16(const void* g, void* l) {
    __builtin_amdgcn_global_load_lds(
        (const __attribute__((address_space(1))) unsigned int*)g,
        (__attribute__((address_space(3))) unsigned int*)l, 16, 0, 0);
}

// ---------- pre-kernel: K f32 -> bf16, fragment-major tiles ----------
__global__ __launch_bounds__(256)
void conv_k_kernel(const float* __restrict__ K, u16* __restrict__ Kp)
{
    const int idx  = (int)blockIdx.x * 256 + (int)threadIdx.x;
    const int lane = idx & 63;
    const int s    = (idx >> 6) & 7;
    const int kt   = (idx >> 9) & 31;
    const int h    = idx >> 14;
    const int mrow = lane & 15;
    const int kg4  = (lane >> 4) << 2;
    const int row  = (s >> 1) * 16 + mrow;
    const int cb   = (s & 1) * 32 + kg4;

    const float* src = K + ((size_t)h * SEQ + (size_t)kt * 64 + row) * DIM + cb;
    const float4 a = *reinterpret_cast<const float4*>(src);
    const float4 b = *reinterpret_cast<const float4*>(src + 16);
    u16x8 o;
    o[0] = (u16)f2bf(a.x); o[1] = (u16)f2bf(a.y); o[2] = (u16)f2bf(a.z); o[3] = (u16)f2bf(a.w);
    o[4] = (u16)f2bf(b.x); o[5] = (u16)f2bf(b.y); o[6] = (u16)f2bf(b.z); o[7] = (u16)f2bf(b.w);
    *reinterpret_cast<u16x8*>(Kp + (size_t)idx * 8) = o;
}

// ---------- pre-kernel: V f32 -> bf16, V^T fragment-major tiles ----------
__global__ __launch_bounds__(256)
void conv_v_kernel(const float* __restrict__ V, u16* __restrict__ Vp)
{
    const int idx  = (int)blockIdx.x * 256 + (int)threadIdx.x;
    const int lane = idx & 63;
    const int s    = (idx >> 6) & 7;
    const int kt   = (idx >> 9) & 31;
    const int h    = idx >> 14;
    const int mrow = lane & 15;
    const int kg4  = (lane >> 4) << 2;
    const int rd   = (s >> 1) * 16 + mrow;
    const int cb   = (s & 1) * 32 + kg4;

    const float* vb = V + ((size_t)h * SEQ + (size_t)kt * 64) * DIM;
    u16x8 o;
    #pragma unroll
    for (int j = 0; j < 4; ++j) {
        o[j]     = (u16)f2bf(vb[(size_t)(cb + j) * DIM + rd]);
        o[4 + j] = (u16)f2bf(vb[(size_t)(cb + 16 + j) * DIM + rd]);
    }
    *reinterpret_cast<u16x8*>(Vp + (size_t)idx * 8) = o;
}

// ---------- main fused kernel: 1024 threads, BQ=256, 3-buffer, 1 barrier/iter ----------
// Pass 1 processes TWO K-tiles per barrier-join (even tile -> Ks slot, odd -> Vs slot).
__global__ __launch_bounds__(1024, 1)
void sdpa_main_kernel(const float* __restrict__ Qp, const u16* __restrict__ Kp,
                      const u16* __restrict__ Vp, const int* __restrict__ Mp,
                      float* __restrict__ Op, float* __restrict__ Pg_)
{
    __shared__ u16   Ks[3][4096];
    __shared__ u16   Vs[3][4096];
    __shared__ float Fb[SEQ];
    __shared__ u16   Pst[16][16][68];  // per-wave P tile (bf16), padded rows

    const int tid  = (int)threadIdx.x;
    const int lane = tid & 63;
    const int w    = tid >> 6;            // wave 0..15, owns q-rows w*16..w*16+15
    const int mrow = lane & 15;
    const int kg4  = (lane >> 4) << 2;

    // XCD-clustered decomposition: 256 blocks (1/CU), xcd = bid & 7.
    const int bid  = (int)blockIdx.x;
    const int xcd  = bid & 7;
    const int slot = bid >> 3;            // 0..31
    const int bh   = xcd * 4 + (slot >> 3);
    const int qt   = slot & 7;            // 8 q-tiles of 256 rows

    const size_t headoff = (size_t)bh * SEQ * DIM;
    const float* Qg = Qp + headoff + (size_t)qt * BQ * DIM;
    const u16*   Kh = Kp + (size_t)bh * NKT * 4096;
    const u16*   Vh = Vp + (size_t)bh * NKT * 4096;
    const int*   Mg = Mp + (size_t)(bh / NH) * SEQ;
    float*       Og = Op + headoff + (size_t)qt * BQ * DIM;
    float*       Pg = Pg_ + ((size_t)bh * SEQ + (size_t)qt * BQ) * SEQ;

    // ---- mask -> additive log2-domain bias in LDS (once) ----
    {
        const int2 m0 = *reinterpret_cast<const int2*>(Mg + tid * 2);
        float2 f0;
        f0.x = m0.x ? -1.0e9f : 0.0f;
        f0.y = m0.y ? -1.0e9f : 0.0f;
        *reinterpret_cast<float2*>(&Fb[tid * 2]) = f0;
    }

    // ---- Q fragments: global -> regs directly (scale folded) ----
    bf16x8 qf0, qf1;
    {
        const float* qrow = Qg + (size_t)(w * 16 + mrow) * DIM;
        const float4 a = *reinterpret_cast<const float4*>(qrow + kg4);
        const float4 b = *reinterpret_cast<const float4*>(qrow + 16 + kg4);
        const float4 c = *reinterpret_cast<const float4*>(qrow + 32 + kg4);
        const float4 d = *reinterpret_cast<const float4*>(qrow + 48 + kg4);
        qf0[0] = f2bf(a.x * QSCALE); qf0[1] = f2bf(a.y * QSCALE);
        qf0[2] = f2bf(a.z * QSCALE); qf0[3] = f2bf(a.w * QSCALE);
        qf0[4] = f2bf(b.x * QSCALE); qf0[5] = f2bf(b.y * QSCALE);
        qf0[6] = f2bf(b.z * QSCALE); qf0[7] = f2bf(b.w * QSCALE);
        qf1[0] = f2bf(c.x * QSCALE); qf1[1] = f2bf(c.y * QSCALE);
        qf1[2] = f2bf(c.z * QSCALE); qf1[3] = f2bf(c.w * QSCALE);
        qf1[4] = f2bf(d.x * QSCALE); qf1[5] = f2bf(d.y * QSCALE);
        qf1[6] = f2bf(d.z * QSCALE); qf1[7] = f2bf(d.w * QSCALE);
    }
    __syncthreads();   // Fb visible to all waves

    // staging roles: waves 0-7 handle even tiles / K, waves 8-15 odd tiles / V
    const int so8 = (tid & 511) * 8;      // offset within an 8KB tile (u16 units)
    const int lo8 = lane * 8;             // lane fragment offset in a frag slot

    // ===== pass 1: lsum — TWO tiles per join (16 iters) =====
    if (w < 8) {
        gll16(Kh + so8, &Ks[0][so8]);                      // tile 0
        gll16(Kh + (size_t)2 * 4096 + so8, &Ks[1][so8]);   // tile 2
    } else {
        gll16(Kh + (size_t)1 * 4096 + so8, &Vs[0][so8]);   // tile 1
        gll16(Kh + (size_t)3 * 4096 + so8, &Vs[1][so8]);   // tile 3
    }

    float lsum = 0.f;
    int bcur = 0, bpre = 2;

    for (int j = 0; j < NKT / 2; ++j) {
        // per-wave queue at top: [G(j), G(j+1)] -> vmcnt(1) retires G(j)
        asm volatile("s_waitcnt vmcnt(1)" ::: "memory");
        __builtin_amdgcn_s_barrier();
        {   // prefetch tile-pair j+2 into slot read at iter j-1 (barrier-safe)
            const int jn = (j + 2) & (NKT / 2 - 1);
            if (w < 8) gll16(Kh + (size_t)(2 * jn) * 4096 + so8, &Ks[bpre][so8]);
            else       gll16(Kh + (size_t)(2 * jn + 1) * 4096 + so8, &Vs[bpre][so8]);
        }
        __builtin_amdgcn_sched_barrier(0);

        const u16* kpe = &Ks[bcur][lo8];   // even tile (2j)
        const u16* kpo = &Vs[bcur][lo8];   // odd tile (2j+1)
        const int k0e = (2 * j) * BK;
        #pragma unroll
        for (int t = 0; t < 4; ++t) {
            const bf16x8 kf0 = *reinterpret_cast<const bf16x8*>(kpe + (2 * t) * 512);
            const bf16x8 kf1 = *reinterpret_cast<const bf16x8*>(kpe + (2 * t + 1) * 512);
            f32x4 a = {0.f, 0.f, 0.f, 0.f};
            a = __builtin_amdgcn_mfma_f32_16x16x32_bf16(kf0, qf0, a, 0, 0, 0);
            a = __builtin_amdgcn_mfma_f32_16x16x32_bf16(kf1, qf1, a, 0, 0, 0);
            const float4 b = *reinterpret_cast<const float4*>(&Fb[k0e + t * 16 + kg4]);
            lsum += __builtin_amdgcn_exp2f(a[0] + b.x);
            lsum += __builtin_amdgcn_exp2f(a[1] + b.y);
            lsum += __builtin_amdgcn_exp2f(a[2] + b.z);
            lsum += __builtin_amdgcn_exp2f(a[3] + b.w);
        }
        #pragma unroll
        for (int t = 0; t < 4; ++t) {
            const bf16x8 kf0 = *reinterpret_cast<const bf16x8*>(kpo + (2 * t) * 512);
            const bf16x8 kf1 = *reinterpret_cast<const bf16x8*>(kpo + (2 * t + 1) * 512);
            f32x4 a = {0.f, 0.f, 0.f, 0.f};
            a = __builtin_amdgcn_mfma_f32_16x16x32_bf16(kf0, qf0, a, 0, 0, 0);
            a = __builtin_amdgcn_mfma_f32_16x16x32_bf16(kf1, qf1, a, 0, 0, 0);
            const float4 b = *reinterpret_cast<const float4*>(&Fb[k0e + BK + t * 16 + kg4]);
            lsum += __builtin_amdgcn_exp2f(a[0] + b.x);
            lsum += __builtin_amdgcn_exp2f(a[1] + b.y);
            lsum += __builtin_amdgcn_exp2f(a[2] + b.z);
            lsum += __builtin_amdgcn_exp2f(a[3] + b.w);
        }

        bcur = (bcur == 2) ? 0 : bcur + 1;
        bpre = (bpre == 2) ? 0 : bpre + 1;
    }

    // drain leftover wraparound prefetches before pass 2 re-stages same buffers
    asm volatile("s_waitcnt vmcnt(0)" ::: "memory");

    lsum += __shfl_xor(lsum, 16);
    lsum += __shfl_xor(lsum, 32);
    const float rinv = 1.0f / lsum;

    __builtin_amdgcn_s_barrier();   // all waves drained before pass-2 staging

    // ===== pass 2: P -> LDS transpose -> coalesced NT store + PV accumulate =====
    f32x4 oacc[4];
    #pragma unroll
    for (int n = 0; n < 4; ++n) {
        oacc[n][0] = 0.f; oacc[n][1] = 0.f; oacc[n][2] = 0.f; oacc[n][3] = 0.f;
    }

    if (w < 8) {
        gll16(Kh + so8, &Ks[0][so8]);
        gll16(Kh + 4096 + so8, &Ks[1][so8]);
    } else {
        gll16(Vh + so8, &Vs[0][so8]);
        gll16(Vh + 4096 + so8, &Vs[1][so8]);
    }
    asm volatile("s_waitcnt vmcnt(1)" ::: "memory");   // peel: tile-0 GLL retired
    __builtin_amdgcn_s_barrier();
    bcur = 0; bpre = 2;

    float* PgW = Pg + (size_t)(w * 16) * SEQ;   // this wave's 16 P rows

    for (int kt = 0; kt < NKT; ++kt) {
        // per-wave queue at top (steady, kt>=2):
        //   [G(kt), S(kt-2)x4, G(kt+1), S(kt-1)x4] = 10 -> vmcnt(9) retires G(kt)
        // kt==1: [G(1), G(2), S(0)x4] = 6 -> vmcnt(5).  kt==0 covered by peel.
        if (kt == 1) { asm volatile("s_waitcnt vmcnt(5)" ::: "memory"); }
        else         { asm volatile("s_waitcnt vmcnt(9)" ::: "memory"); }
        __builtin_amdgcn_s_barrier();
        {   // prefetch tile kt+2 into buffer read at iter kt-1 (safe per barrier)
            const size_t nt = (size_t)((kt + 2) & (NKT - 1)) * 4096;
            if (w < 8) gll16(Kh + nt + so8, &Ks[bpre][so8]);
            else       gll16(Vh + nt + so8, &Vs[bpre][so8]);
        }
        __builtin_amdgcn_sched_barrier(0);

        const u16* kp = &Ks[bcur][lo8];
        const u16* vp = &Vs[bcur][lo8];
        const int k0 = kt * BK;
        bf16x8 pf0, pf1;

        #pragma unroll
        for (int half = 0; half < 2; ++half) {
            f32x4 p[2];
            #pragma unroll
            for (int i = 0; i < 2; ++i) {
                const int t = half * 2 + i;
                const bf16x8 kf0 = *reinterpret_cast<const bf16x8*>(kp + (2 * t) * 512);
                const bf16x8 kf1 = *reinterpret_cast<const bf16x8*>(kp + (2 * t + 1) * 512);
                f32x4 a = {0.f, 0.f, 0.f, 0.f};
                a = __builtin_amdgcn_mfma_f32_16x16x32_bf16(kf0, qf0, a, 0, 0, 0);
                a = __builtin_amdgcn_mfma_f32_16x16x32_bf16(kf1, qf1, a, 0, 0, 0);
                const float4 b = *reinterpret_cast<const float4*>(&Fb[k0 + t * 16 + kg4]);
                p[i][0] = __builtin_amdgcn_exp2f(a[0] + b.x) * rinv;
                p[i][1] = __builtin_amdgcn_exp2f(a[1] + b.y) * rinv;
                p[i][2] = __builtin_amdgcn_exp2f(a[2] + b.z) * rinv;
                p[i][3] = __builtin_amdgcn_exp2f(a[3] + b.w) * rinv;
            }
            const u32x4 packed = { cvtpk(p[0][0], p[0][1]), cvtpk(p[0][2], p[0][3]),
                                   cvtpk(p[1][0], p[1][1]), cvtpk(p[1][2], p[1][3]) };
            if (half == 0) pf0 = __builtin_bit_cast(bf16x8, packed);
            else           pf1 = __builtin_bit_cast(bf16x8, packed);
        }

        // stage P tile (bf16) into wave-private LDS
        {
            const u16x4* f0 = reinterpret_cast<const u16x4*>(&pf0);
            const u16x4* f1 = reinterpret_cast<const u16x4*>(&pf1);
            *reinterpret_cast<u16x4*>(&Pst[w][mrow][kg4])      = f0[0];
            *reinterpret_cast<u16x4*>(&Pst[w][mrow][16 + kg4]) = f0[1];
            *reinterpret_cast<u16x4*>(&Pst[w][mrow][32 + kg4]) = f1[0];
            *reinterpret_cast<u16x4*>(&Pst[w][mrow][48 + kg4]) = f1[1];
        }

        #pragma unroll
        for (int n = 0; n < 4; ++n) {
            const bf16x8 vf0 = *reinterpret_cast<const bf16x8*>(vp + (2 * n) * 512);
            const bf16x8 vf1 = *reinterpret_cast<const bf16x8*>(vp + (2 * n + 1) * 512);
            oacc[n] = __builtin_amdgcn_mfma_f32_16x16x32_bf16(pf0, vf0, oacc[n], 0, 0, 0);
            oacc[n] = __builtin_amdgcn_mfma_f32_16x16x32_bf16(pf1, vf1, oacc[n], 0, 0, 0);
        }

        // coalesced NT P store: instr j covers 4 rows x 256B contiguous
        // (full 128B-line coverage -> NT partial-line penalty from R11 doesn't apply;
        //  bypassing L2 write-allocate protects the pinned K/V working set)
        #pragma unroll
        for (int j = 0; j < 4; ++j) {
            const u16x4 r = *reinterpret_cast<const u16x4*>(
                &Pst[w][j * 4 + (lane >> 4)][(lane & 15) * 4]);
            f32x4 f;
            f[0] = __uint_as_float((unsigned)r[0] << 16);
            f[1] = __uint_as_float((unsigned)r[1] << 16);
            f[2] = __uint_as_float((unsigned)r[2] << 16);
            f[3] = __uint_as_float((unsigned)r[3] << 16);
            __builtin_nontemporal_store(
                f, reinterpret_cast<f32x4*>(
                       PgW + (size_t)(j * 4 + (lane >> 4)) * SEQ + k0 + 4 * (lane & 15)));
        }

        bcur = (bcur == 2) ? 0 : bcur + 1;
        bpre = (bpre == 2) ? 0 : bpre + 1;
    }

    #pragma unroll
    for (int n = 0; n < 4; ++n) {
        #pragma unroll
        for (int r = 0; r < 4; ++r)
            Og[(size_t)(w * 16 + kg4 + r) * DIM + n * 16 + mrow] = oacc[n][r];
    }
}

extern "C" void kernel_launch(void* const* d_in, const int* in_sizes, int n_in,
                              void* d_out, int out_size, void* d_ws, size_t ws_size,
                              hipStream_t stream) {
    const float* Q = (const float*)d_in[0];
    const float* K = (const float*)d_in[1];
    const float* V = (const float*)d_in[2];
    const int*   M = (const int*)d_in[3];
    float* O = (float*)d_out;
    float* P = O + (size_t)NB * NH * SEQ * DIM;

    u16* Kp = (u16*)d_ws;                                   // 8 MB
    u16* Vp = Kp + (size_t)NHEAD * SEQ * DIM;               // 8 MB (total exactly 16 MB)

    const int conv_blocks = NHEAD * NKT * 8 * 64 / 256;     // 2048
    conv_k_kernel<<<dim3(conv_blocks), dim3(256), 0, stream>>>(K, Kp);
    conv_v_kernel<<<dim3(conv_blocks), dim3(256), 0, stream>>>(V, Vp);

    sdpa_main_kernel<<<dim3(NHEAD * NQT), dim3(1024, 1, 1), 0, stream>>>(Q, Kp, Vp, M, O, P);
}